// Round 17
// baseline (136.267 us; speedup 1.0000x reference)
//
#include <hip/hip_runtime.h>
#include <hip/hip_bf16.h>

typedef __bf16 bf16_t;
typedef __bf16 bf16x8 __attribute__((ext_vector_type(8)));
typedef __bf16 bf16x4 __attribute__((ext_vector_type(4)));
typedef float f32x4 __attribute__((ext_vector_type(4)));
typedef int vint4 __attribute__((ext_vector_type(4)));

#define AS1 __attribute__((address_space(1)))
#define AS3 __attribute__((address_space(3)))

constexpr int B_ = 2, T_ = 4096, E_ = 1024, H_ = 16;
constexpr int M_ = B_ * T_;   // 8192 token rows

// Compact per-scale partial buffers (elem offsets); scales 1-4 used (s0 merges inline).
__device__ constexpr size_t OB_OFF[5]  = {0, 8388608, 12582912, 14680064, 15728640};
__device__ constexpr size_t LSE_OFF[5] = {0, 131072, 196608, 229376, 245760};
constexpr size_t OB_TOTAL  = 16252928;  // elems (bf16)
constexpr size_t LSE_TOTAL = 253952;    // elems (f32)

// ---------------- f32 -> bf16 elementwise ----------------
__global__ __launch_bounds__(256) void cvt_f32_bf16(const float* __restrict__ in,
                                                    bf16_t* __restrict__ out) {
  int i = (blockIdx.x * 256 + threadIdx.x) * 4;
  const float4 v = *(const float4*)(in + i);
  bf16x4 o;
  o[0] = (bf16_t)v.x; o[1] = (bf16_t)v.y; o[2] = (bf16_t)v.z; o[3] = (bf16_t)v.w;
  *(bf16x4*)(out + i) = o;
}

// ---------------- weights: f32 [K][N] -> bf16 [N][K] (transposed) ----------------
__global__ __launch_bounds__(256) void cvt_transpose_w(
    const float* __restrict__ w0, const float* __restrict__ w1,
    const float* __restrict__ w2, const float* __restrict__ w3,
    bf16_t* __restrict__ o0, bf16_t* __restrict__ o1,
    bf16_t* __restrict__ o2, bf16_t* __restrict__ o3) {
  __shared__ float tile[32][33];
  const float* src; bf16_t* dst;
  switch (blockIdx.z) {
    case 0: src = w0; dst = o0; break;
    case 1: src = w1; dst = o1; break;
    case 2: src = w2; dst = o2; break;
    default: src = w3; dst = o3; break;
  }
  const int n0 = blockIdx.x * 32, k0 = blockIdx.y * 32;
  const int tx = threadIdx.x & 31, ty = threadIdx.x >> 5;  // 32 x 8
#pragma unroll
  for (int i = 0; i < 32; i += 8)
    tile[ty + i][tx] = src[(size_t)(k0 + ty + i) * E_ + n0 + tx];
  __syncthreads();
#pragma unroll
  for (int i = 0; i < 32; i += 8)
    dst[(size_t)(n0 + ty + i) * E_ + k0 + tx] = (bf16_t)tile[tx][ty + i];
}

// ---------------- 128x128 single-buffer GEMM + XOR swizzle (958 TF measured, R11) ----
// QKV instantiation pads LDS to 48 KB -> exactly 3 blocks/CU -> grid 1536 runs as
// 2 perfectly-even rounds (was 4/CU: 1024 + 512 tail, ~25% machine idle).
template <bool OUT_BF16, bool QKV>
__global__ __launch_bounds__(256, 4) void gemm_bt(
    const bf16_t* __restrict__ A, const bf16_t* __restrict__ BT,
    const float* __restrict__ bias0, const float* __restrict__ bias1,
    const float* __restrict__ bias2, void* __restrict__ Cout, float qscale) {
  constexpr int K = E_;
  __shared__ bf16_t As[128 * 64];
  __shared__ bf16_t Bs[128 * 64];
  const int tid = threadIdx.x;
  const int lane = tid & 63;
  const int wave = tid >> 6;
  const int wm = wave >> 1, wn = wave & 1;
  const int lc = lane & 15, lg = lane >> 4;
  const int bm = blockIdx.x;
  int bn = blockIdx.y;

  if constexpr (QKV) {
    // 16 KB occupancy pad: forces 3 blocks/CU (even 2-round schedule for 1536 blocks)
    __shared__ bf16_t pad_[8192];
    if ((int)blockIdx.x == -1) ((volatile bf16_t*)pad_)[0] = (bf16_t)0.f;
  }

  const float* bias = bias0;
  float scale = 1.0f;
  void* outp = Cout;
  const bf16_t* Bt = BT;
  if (QKV) {
    const int which = bn >> 3;
    bn &= 7;
    bias = (which == 0) ? bias0 : (which == 1) ? bias1 : bias2;
    scale = (which == 0) ? qscale : 1.0f;
    outp = (void*)((bf16_t*)Cout + (size_t)which * M_ * E_);
    Bt += (size_t)which * E_ * E_;
  }

  f32x4 acc[4][4] = {};

  const int lrow = tid >> 3;                    // 0..31
  const int schunk = (tid & 7) ^ (lrow & 7);    // source-side swizzle
  const bf16_t* Ag = A + (size_t)(bm * 128 + lrow) * K + schunk * 8;
  const bf16_t* Bg = Bt + (size_t)(bn * 128 + lrow) * K + schunk * 8;

  const int sl0 = ((0 * 4 + lg) ^ (lc & 7)) * 8;
  const int sl1 = ((1 * 4 + lg) ^ (lc & 7)) * 8;

  for (int k0 = 0; k0 < K; k0 += 64) {
    __syncthreads();
#pragma unroll
    for (int p = 0; p < 4; ++p) {
      __builtin_amdgcn_global_load_lds(
          (const AS1 void*)(Ag + (size_t)(p * 32) * K + k0),
          (AS3 void*)(As + p * 2048 + tid * 8), 16, 0, 0);
      __builtin_amdgcn_global_load_lds(
          (const AS1 void*)(Bg + (size_t)(p * 32) * K + k0),
          (AS3 void*)(Bs + p * 2048 + tid * 8), 16, 0, 0);
    }
    __syncthreads();
#pragma unroll
    for (int kk = 0; kk < 2; ++kk) {
      const int sl = kk ? sl1 : sl0;
      bf16x8 af[4], bfr[4];
#pragma unroll
      for (int i = 0; i < 4; ++i) {
        af[i]  = *(const bf16x8*)&As[(wm * 64 + i * 16 + lc) * 64 + sl];
        bfr[i] = *(const bf16x8*)&Bs[(wn * 64 + i * 16 + lc) * 64 + sl];
      }
#pragma unroll
      for (int i = 0; i < 4; ++i)
#pragma unroll
        for (int j = 0; j < 4; ++j)
          acc[i][j] = __builtin_amdgcn_mfma_f32_16x16x32_bf16(af[i], bfr[j], acc[i][j], 0, 0, 0);
    }
  }

#pragma unroll
  for (int i = 0; i < 4; ++i) {
    const int row = bm * 128 + wm * 64 + i * 16 + lg * 4;
#pragma unroll
    for (int j = 0; j < 4; ++j) {
      const int col = bn * 128 + wn * 64 + j * 16 + lc;
      const float bv = bias[col];
#pragma unroll
      for (int rg = 0; rg < 4; ++rg) {
        const float v = (acc[i][j][rg] + bv) * scale;
        if (OUT_BF16)
          ((bf16_t*)outp)[(size_t)(row + rg) * E_ + col] = (bf16_t)v;
        else
          ((float*)outp)[(size_t)(row + rg) * E_ + col] = v;
      }
    }
  }
}

// ---------------- uniform causal-256 flash instance, pipelined PV (lag-1) ------------
template <bool S0>
__global__ __launch_bounds__(512, 4) void attn_inst(
    const bf16_t* __restrict__ Q, const bf16_t* __restrict__ K,
    const bf16_t* __restrict__ V, bf16_t* __restrict__ Ob,
    float* __restrict__ Lse, bf16_t* __restrict__ Y) {
  __shared__ alignas(16) bf16_t Ks[256 * 64];   // 32768 B (linear, src-XOR swizzled)
  __shared__ alignas(16) bf16_t Vt[64 * 256];   // 32768 B (col-XOR swizzled)
  __shared__ alignas(16) bf16_t Pw[8 * 16 * 64];// 16384 B (both halves, XOR swizzled)

  const int bid = blockIdx.x;
  int s, ibase;
  if (S0) { s = 0; ibase = 0; }
  else if (bid < 256) { s = 1; ibase = 0; }
  else if (bid < 384) { s = 2; ibase = 256; }
  else if (bid < 448) { s = 3; ibase = 384; }
  else                { s = 4; ibase = 448; }
  const int inst = bid - ibase;
  const int h = inst & 15;
  const int nseg_log = 4 - s;
  const int seg = (inst >> 4) & ((1 << nseg_log) - 1);
  const int b = inst >> (4 + nseg_log);
  const int g = h >> (4 - s);      // dilation offset for this head group

  const int t = threadIdx.x;
  const int lane = t & 63;
  const int wv = t >> 6;
  const int lc = lane & 15;
  const int lg = lane >> 4;

  // ---- stage K: 4x global_load_lds, linear dest, source chunk XOR (row&7) ----
  {
    const int krow = t >> 3;                          // 0..63
    const int kch = ((t & 7) ^ (krow & 7)) * 8;       // source-side swizzle
#pragma unroll
    for (int p = 0; p < 4; ++p) {
      const int tk = ((seg * 256 + krow + p * 64) << s) + g;
      __builtin_amdgcn_global_load_lds(
          (const AS1 void*)(K + ((size_t)b * T_ + tk) * E_ + h * 64 + kch),
          (AS3 void*)(Ks + p * 4096 + t * 8), 16, 0, 0);
    }
  }
  // ---- stage V transposed: 4 bf16x8 loads -> 8 ds_write_b64 (col-XOR layout) ----
  {
    const int r0 = (t & 63) * 4;          // 4-key group
    const int d0 = (t >> 6) * 8;          // 8-d group (one per wave)
    bf16x8 va[4];
#pragma unroll
    for (int rr = 0; rr < 4; ++rr) {
      const int tk = ((seg * 256 + r0 + rr) << s) + g;
      va[rr] = *(const bf16x8*)(V + ((size_t)b * T_ + tk) * E_ + h * 64 + d0);
    }
#pragma unroll
    for (int d = 0; d < 8; ++d) {
      bf16x4 w;
      w[0] = va[0][d]; w[1] = va[1][d]; w[2] = va[2][d]; w[3] = va[3][d];
      *(bf16x4*)&Vt[(d0 + d) * 256 + (r0 ^ ((d & 7) << 3))] = w;
    }
  }
  __syncthreads();

  const size_t rowbase = (size_t)(b * H_ + h) * (T_ >> s) + seg * 256;
  bf16_t* PwRow = &Pw[wv * 1024 + lc * 64];
  const int kxor = (lc & 7);

#pragma unroll
  for (int sel = 0; sel < 2; ++sel) {
    const int tile = sel ? (15 - wv) : wv;   // causal load-balance pairing
    const int q = tile * 16 + lc;            // this lane's query row (swapped layout)

    const int tq = ((seg * 256 + q) << s) + g;
    const bf16_t* Qg = Q + ((size_t)b * T_ + tq) * E_ + h * 64 + lg * 8;
    bf16x8 qfrag0 = *(const bf16x8*)(Qg);
    bf16x8 qfrag1 = *(const bf16x8*)(Qg + 32);

    float m = -INFINITY, Zp = 0.0f;
    f32x4 Oa[4] = {};

    const int nkb = tile / 4 + 1;   // 64-key blocks (causal)
    const int diag = tile / 4;
    for (int kb = 0; kb < nkb; ++kb) {
      // ---- QK(kb): S^T = K Q^T, lane holds S[key=kt*16+lg*4+rg][q=lc] ----
      f32x4 sacc[4] = {};
      __builtin_amdgcn_s_setprio(1);
#pragma unroll
      for (int kt = 0; kt < 4; ++kt) {
        const int krow = kb * 64 + kt * 16 + lc;      // krow&7 == lc&7
        bf16x8 kf0 = *(const bf16x8*)&Ks[krow * 64 + ((0 + lg) ^ kxor) * 8];
        bf16x8 kf1 = *(const bf16x8*)&Ks[krow * 64 + ((4 + lg) ^ kxor) * 8];
        sacc[kt] = __builtin_amdgcn_mfma_f32_16x16x32_bf16(kf0, qfrag0, sacc[kt], 0, 0, 0);
        sacc[kt] = __builtin_amdgcn_mfma_f32_16x16x32_bf16(kf1, qfrag1, sacc[kt], 0, 0, 0);
      }
      // ---- PV(kb-1): independent of QK(kb); single Pw buffer race-free (in-order) ----
      if (kb > 0) {
#pragma unroll
        for (int hf = 0; hf < 2; ++hf) {
          bf16x8 pb = *(const bf16x8*)&PwRow[(hf * 32 + lg * 8) ^ (kxor * 8)];
#pragma unroll
          for (int dt = 0; dt < 4; ++dt) {
            const int vrow = dt * 16 + lc;
            const int vcol = (((kb - 1) * 2 + hf) * 32 + lg * 8) ^ (kxor << 3);
            bf16x8 vf = *(const bf16x8*)&Vt[vrow * 256 + vcol];
            Oa[dt] = __builtin_amdgcn_mfma_f32_16x16x32_bf16(vf, pb, Oa[dt], 0, 0, 0);
          }
        }
      }
      __builtin_amdgcn_s_setprio(0);
      // ---- mask + softmax(kb) ----
      if (kb == diag) {
#pragma unroll
        for (int kt = 0; kt < 4; ++kt)
#pragma unroll
          for (int rg = 0; rg < 4; ++rg)
            if (kb * 64 + kt * 16 + lg * 4 + rg > q) sacc[kt][rg] = -1e30f;
      }
      float pm = -1e30f;
#pragma unroll
      for (int kt = 0; kt < 4; ++kt) {
        pm = fmaxf(pm, fmaxf(fmaxf(sacc[kt][0], sacc[kt][1]),
                             fmaxf(sacc[kt][2], sacc[kt][3])));
      }
      pm = fmaxf(pm, __shfl_xor(pm, 16));
      pm = fmaxf(pm, __shfl_xor(pm, 32));
      if (!__all(pm - m <= 11.5f)) {
        const float nm = fmaxf(m, pm);
        const float crr = __builtin_amdgcn_exp2f(m - nm);
        Zp *= crr;
#pragma unroll
        for (int dt = 0; dt < 4; ++dt)
#pragma unroll
          for (int rg = 0; rg < 4; ++rg) Oa[dt][rg] *= crr;
        m = nm;
      }
#pragma unroll
      for (int kt = 0; kt < 4; ++kt) {
        bf16x4 pv;
#pragma unroll
        for (int rg = 0; rg < 4; ++rg) {
          const float p = __builtin_amdgcn_exp2f(sacc[kt][rg] - m);
          Zp += p;
          pv[rg] = (bf16_t)p;
        }
        const int clog = (kt >> 1) * 32 + (kt & 1) * 16 + lg * 4;
        *(bf16x4*)&PwRow[clog ^ (kxor << 3)] = pv;
      }
    }
    // ---- drain PV(nkb-1) ----
    __builtin_amdgcn_s_setprio(1);
#pragma unroll
    for (int hf = 0; hf < 2; ++hf) {
      bf16x8 pb = *(const bf16x8*)&PwRow[(hf * 32 + lg * 8) ^ (kxor * 8)];
#pragma unroll
      for (int dt = 0; dt < 4; ++dt) {
        const int vrow = dt * 16 + lc;
        const int vcol = (((nkb - 1) * 2 + hf) * 32 + lg * 8) ^ (kxor << 3);
        bf16x8 vf = *(const bf16x8*)&Vt[vrow * 256 + vcol];
        Oa[dt] = __builtin_amdgcn_mfma_f32_16x16x32_bf16(vf, pb, Oa[dt], 0, 0, 0);
      }
    }
    __builtin_amdgcn_s_setprio(0);

    // ---- epilogue: reduce Z across the 4 lane-groups; lse is base-2 ----
    float Z = Zp + __shfl_xor(Zp, 16);
    Z = Z + __shfl_xor(Z, 32);
    const float lse = m + __builtin_amdgcn_logf(Z);
    const float iZ = 1.0f / Z;
    if (!S0) {
      bf16_t* orow = Ob + OB_OFF[s] + (rowbase + q) * 64 + lg * 4;
#pragma unroll
      for (int dt = 0; dt < 4; ++dt) {
        bf16x4 ov;
        ov[0] = (bf16_t)(Oa[dt][0] * iZ);
        ov[1] = (bf16_t)(Oa[dt][1] * iZ);
        ov[2] = (bf16_t)(Oa[dt][2] * iZ);
        ov[3] = (bf16_t)(Oa[dt][3] * iZ);
        *(bf16x4*)(orow + dt * 16) = ov;
      }
      if (lg == 0) Lse[LSE_OFF[s] + rowbase + q] = lse;
    } else {
      const int t_glob = seg * 256 + q;          // s=0 -> global position
      // issue ALL merge loads in parallel (always in-bounds; coverage gates weight)
      float l2v[4];
      bf16x4 ovv[4][4];
#pragma unroll
      for (int s2 = 1; s2 <= 4; ++s2) {
        const size_t idx = (size_t)(b * H_ + h) * (T_ >> s2) + (t_glob >> s2);
        l2v[s2 - 1] = Lse[LSE_OFF[s2] + idx];
        const bf16_t* orow = Ob + OB_OFF[s2] + idx * 64 + lg * 4;
#pragma unroll
        for (int dt = 0; dt < 4; ++dt)
          ovv[s2 - 1][dt] = *(const bf16x4*)(orow + dt * 16);
      }
      float o16[4][4];
#pragma unroll
      for (int dt = 0; dt < 4; ++dt)
#pragma unroll
        for (int rg = 0; rg < 4; ++rg) o16[dt][rg] = Oa[dt][rg] * iZ;
      float M = lse, S = 1.0f;
#pragma unroll
      for (int s2 = 1; s2 <= 4; ++s2) {
        const int r = 1 << s2;
        const int gg = h >> (4 - s2);
        const bool cov = ((t_glob & (r - 1)) == gg);
        const float l2 = cov ? l2v[s2 - 1] : -INFINITY;
        const float nM = fmaxf(M, l2);
        const float a = __builtin_amdgcn_exp2f(M - nM);
        const float e = __builtin_amdgcn_exp2f(l2 - nM);
#pragma unroll
        for (int dt = 0; dt < 4; ++dt)
#pragma unroll
          for (int rg = 0; rg < 4; ++rg)
            o16[dt][rg] = o16[dt][rg] * a + (float)ovv[s2 - 1][dt][rg] * e;
        S = S * a + e;
        M = nM;
      }
      const float invS = 1.0f / S;
      bf16_t* yrow = Y + ((size_t)b * T_ + t_glob) * E_ + h * 64 + lg * 4;
#pragma unroll
      for (int dt = 0; dt < 4; ++dt) {
        bf16x4 ov;
        ov[0] = (bf16_t)(o16[dt][0] * invS);
        ov[1] = (bf16_t)(o16[dt][1] * invS);
        ov[2] = (bf16_t)(o16[dt][2] * invS);
        ov[3] = (bf16_t)(o16[dt][3] * invS);
        *(bf16x4*)(yrow + dt * 16) = ov;
      }
    }
  }
}

extern "C" void kernel_launch(void* const* d_in, const int* in_sizes, int n_in,
                              void* d_out, int out_size, void* d_ws, size_t ws_size,
                              hipStream_t stream) {
  (void)in_sizes; (void)n_in; (void)out_size; (void)ws_size;
  const float* x  = (const float*)d_in[0];
  const float* wq = (const float*)d_in[1];
  const float* bq = (const float*)d_in[2];
  const float* wk = (const float*)d_in[3];
  const float* bk = (const float*)d_in[4];
  const float* wv = (const float*)d_in[5];
  const float* bv = (const float*)d_in[6];
  const float* wo = (const float*)d_in[7];
  const float* bo = (const float*)d_in[8];

  char* p = (char*)d_ws;
  auto take = [&](size_t bytes) {
    char* q = p;
    p += (bytes + 255) & ~(size_t)255;
    return (void*)q;
  };
  bf16_t* wq_t = (bf16_t*)take((size_t)E_ * E_ * 2);  // wq_t/wk_t/wv_t contiguous
  bf16_t* wk_t = (bf16_t*)take((size_t)E_ * E_ * 2);
  bf16_t* wv_t = (bf16_t*)take((size_t)E_ * E_ * 2);
  bf16_t* wo_t = (bf16_t*)take((size_t)E_ * E_ * 2);
  bf16_t* xb   = (bf16_t*)take((size_t)M_ * E_ * 2);
  bf16_t* qb   = (bf16_t*)take((size_t)M_ * E_ * 2);  // qb/kbuf/vbuf contiguous
  bf16_t* kbuf = (bf16_t*)take((size_t)M_ * E_ * 2);
  bf16_t* vbuf = (bf16_t*)take((size_t)M_ * E_ * 2);
  bf16_t* yb   = (bf16_t*)take((size_t)M_ * E_ * 2);
  bf16_t* Ob   = (bf16_t*)take(OB_TOTAL * 2);
  float*  Lse  = (float*)take(LSE_TOTAL * 4);
  (void)wk_t; (void)wv_t;

  cvt_f32_bf16<<<M_ * E_ / 1024, 256, 0, stream>>>(x, xb);
  cvt_transpose_w<<<dim3(32, 32, 4), 256, 0, stream>>>(wq, wk, wv, wo, wq_t, wk_t, wv_t, wo_t);

  // Fused Q/K/V projection: 128x128 tiles, forced 3 blocks/CU (even 2-round grid).
  gemm_bt<true, true><<<dim3(M_ / 128, 24), 256, 0, stream>>>(
      xb, wq_t, bq, bk, bv, qb, 0.125f * 1.44269504f);

  // Scales 1-4 (480 blocks) -> compact Ob/Lse.
  attn_inst<false><<<480, 512, 0, stream>>>(qb, kbuf, vbuf, Ob, Lse, yb);
  // Scale 0 (512 blocks) + parallel-load in-register merge + y write.
  attn_inst<true><<<512, 512, 0, stream>>>(qb, kbuf, vbuf, Ob, Lse, yb);

  // Output projection.
  gemm_bt<false, false><<<dim3(M_ / 128, 8), 256, 0, stream>>>(
      yb, wo_t, bo, bo, bo, d_out, 1.0f);
}

// Round 18
// 126.528 us; speedup vs baseline: 1.0770x; 1.0770x over previous
//
#include <hip/hip_runtime.h>
#include <hip/hip_bf16.h>

typedef __bf16 bf16_t;
typedef __bf16 bf16x8 __attribute__((ext_vector_type(8)));
typedef __bf16 bf16x4 __attribute__((ext_vector_type(4)));
typedef float f32x4 __attribute__((ext_vector_type(4)));
typedef int vint4 __attribute__((ext_vector_type(4)));

#define AS1 __attribute__((address_space(1)))
#define AS3 __attribute__((address_space(3)))

constexpr int B_ = 2, T_ = 4096, E_ = 1024, H_ = 16;
constexpr int M_ = B_ * T_;   // 8192 token rows

// Compact per-scale partial buffers (elem offsets); scales 1-4 used (s0 merges inline).
__device__ constexpr size_t OB_OFF[5]  = {0, 8388608, 12582912, 14680064, 15728640};
__device__ constexpr size_t LSE_OFF[5] = {0, 131072, 196608, 229376, 245760};
constexpr size_t OB_TOTAL  = 16252928;  // elems (bf16)
constexpr size_t LSE_TOTAL = 253952;    // elems (f32)

// ---------------- f32 -> bf16 elementwise ----------------
__global__ __launch_bounds__(256) void cvt_f32_bf16(const float* __restrict__ in,
                                                    bf16_t* __restrict__ out) {
  int i = (blockIdx.x * 256 + threadIdx.x) * 4;
  const float4 v = *(const float4*)(in + i);
  bf16x4 o;
  o[0] = (bf16_t)v.x; o[1] = (bf16_t)v.y; o[2] = (bf16_t)v.z; o[3] = (bf16_t)v.w;
  *(bf16x4*)(out + i) = o;
}

// ---------------- weights: f32 [K][N] -> bf16 [N][K] (transposed) ----------------
__global__ __launch_bounds__(256) void cvt_transpose_w(
    const float* __restrict__ w0, const float* __restrict__ w1,
    const float* __restrict__ w2, const float* __restrict__ w3,
    bf16_t* __restrict__ o0, bf16_t* __restrict__ o1,
    bf16_t* __restrict__ o2, bf16_t* __restrict__ o3) {
  __shared__ float tile[32][33];
  const float* src; bf16_t* dst;
  switch (blockIdx.z) {
    case 0: src = w0; dst = o0; break;
    case 1: src = w1; dst = o1; break;
    case 2: src = w2; dst = o2; break;
    default: src = w3; dst = o3; break;
  }
  const int n0 = blockIdx.x * 32, k0 = blockIdx.y * 32;
  const int tx = threadIdx.x & 31, ty = threadIdx.x >> 5;  // 32 x 8
#pragma unroll
  for (int i = 0; i < 32; i += 8)
    tile[ty + i][tx] = src[(size_t)(k0 + ty + i) * E_ + n0 + tx];
  __syncthreads();
#pragma unroll
  for (int i = 0; i < 32; i += 8)
    dst[(size_t)(n0 + ty + i) * E_ + k0 + tx] = (bf16_t)tile[tx][ty + i];
}

// ---------------- 128x128 single-buffer GEMM + XOR swizzle (958 TF measured, R11) ----
template <bool OUT_BF16, bool QKV>
__global__ __launch_bounds__(256, 4) void gemm_bt(
    const bf16_t* __restrict__ A, const bf16_t* __restrict__ BT,
    const float* __restrict__ bias0, const float* __restrict__ bias1,
    const float* __restrict__ bias2, void* __restrict__ Cout, float qscale) {
  constexpr int K = E_;
  __shared__ bf16_t As[128 * 64];
  __shared__ bf16_t Bs[128 * 64];
  const int tid = threadIdx.x;
  const int lane = tid & 63;
  const int wave = tid >> 6;
  const int wm = wave >> 1, wn = wave & 1;
  const int lc = lane & 15, lg = lane >> 4;
  const int bm = blockIdx.x;
  int bn = blockIdx.y;

  const float* bias = bias0;
  float scale = 1.0f;
  void* outp = Cout;
  const bf16_t* Bt = BT;
  if (QKV) {
    const int which = bn >> 3;
    bn &= 7;
    bias = (which == 0) ? bias0 : (which == 1) ? bias1 : bias2;
    scale = (which == 0) ? qscale : 1.0f;
    outp = (void*)((bf16_t*)Cout + (size_t)which * M_ * E_);
    Bt += (size_t)which * E_ * E_;
  }

  f32x4 acc[4][4] = {};

  const int lrow = tid >> 3;                    // 0..31
  const int schunk = (tid & 7) ^ (lrow & 7);    // source-side swizzle
  const bf16_t* Ag = A + (size_t)(bm * 128 + lrow) * K + schunk * 8;
  const bf16_t* Bg = Bt + (size_t)(bn * 128 + lrow) * K + schunk * 8;

  const int sl0 = ((0 * 4 + lg) ^ (lc & 7)) * 8;
  const int sl1 = ((1 * 4 + lg) ^ (lc & 7)) * 8;

  for (int k0 = 0; k0 < K; k0 += 64) {
    __syncthreads();
#pragma unroll
    for (int p = 0; p < 4; ++p) {
      __builtin_amdgcn_global_load_lds(
          (const AS1 void*)(Ag + (size_t)(p * 32) * K + k0),
          (AS3 void*)(As + p * 2048 + tid * 8), 16, 0, 0);
      __builtin_amdgcn_global_load_lds(
          (const AS1 void*)(Bg + (size_t)(p * 32) * K + k0),
          (AS3 void*)(Bs + p * 2048 + tid * 8), 16, 0, 0);
    }
    __syncthreads();
#pragma unroll
    for (int kk = 0; kk < 2; ++kk) {
      const int sl = kk ? sl1 : sl0;
      bf16x8 af[4], bfr[4];
#pragma unroll
      for (int i = 0; i < 4; ++i) {
        af[i]  = *(const bf16x8*)&As[(wm * 64 + i * 16 + lc) * 64 + sl];
        bfr[i] = *(const bf16x8*)&Bs[(wn * 64 + i * 16 + lc) * 64 + sl];
      }
#pragma unroll
      for (int i = 0; i < 4; ++i)
#pragma unroll
        for (int j = 0; j < 4; ++j)
          acc[i][j] = __builtin_amdgcn_mfma_f32_16x16x32_bf16(af[i], bfr[j], acc[i][j], 0, 0, 0);
    }
  }

#pragma unroll
  for (int i = 0; i < 4; ++i) {
    const int row = bm * 128 + wm * 64 + i * 16 + lg * 4;
#pragma unroll
    for (int j = 0; j < 4; ++j) {
      const int col = bn * 128 + wn * 64 + j * 16 + lc;
      const float bv = bias[col];
#pragma unroll
      for (int rg = 0; rg < 4; ++rg) {
        const float v = (acc[i][j][rg] + bv) * scale;
        if (OUT_BF16)
          ((bf16_t*)outp)[(size_t)(row + rg) * E_ + col] = (bf16_t)v;
        else
          ((float*)outp)[(size_t)(row + rg) * E_ + col] = v;
      }
    }
  }
}

// ---------------- uniform causal-256 flash instance, base-2 softmax (HW exp) ---------
// S0=false (LATE): 480 blocks = scales 1-4 -> write compact Ob/Lse.
// S0=true: 512 blocks = scale 0 (covers every (b,t,h)); epilogue merges the <=4
// covering late-scale (Ob,Lse) entries in-register (online base-2 LSE) and writes
// yb directly -- no scale-0 Ob round-trip, no separate merge dispatch.
template <bool S0>
__global__ __launch_bounds__(512, 4) void attn_inst(
    const bf16_t* __restrict__ Q, const bf16_t* __restrict__ K,
    const bf16_t* __restrict__ V, bf16_t* __restrict__ Ob,
    float* __restrict__ Lse, bf16_t* __restrict__ Y) {
  __shared__ alignas(16) bf16_t Ks[256][72];   // 36864 B
  __shared__ alignas(16) bf16_t Vt[64][264];   // 33792 B
  __shared__ alignas(16) bf16_t Pw[8][16][40]; // 10240 B  (80896 B -> 2 blocks/CU)

  const int bid = blockIdx.x;
  int s, ibase;
  if (S0) { s = 0; ibase = 0; }
  else if (bid < 256) { s = 1; ibase = 0; }
  else if (bid < 384) { s = 2; ibase = 256; }
  else if (bid < 448) { s = 3; ibase = 384; }
  else                { s = 4; ibase = 448; }
  const int inst = bid - ibase;
  const int h = inst & 15;
  const int nseg_log = 4 - s;
  const int seg = (inst >> 4) & ((1 << nseg_log) - 1);
  const int b = inst >> (4 + nseg_log);
  const int g = h >> (4 - s);      // dilation offset for this head group

  const int t = threadIdx.x;
  const int lane = t & 63;
  const int wv = t >> 6;
  const int lc = lane & 15;
  const int lg = lane >> 4;

  // ---- stage K (row-major, padded) and V (transposed) ----
  {
    const int row = t >> 1, ch = (t & 1) * 32;
    const int tk = ((seg * 256 + row) << s) + g;
    const size_t off = ((size_t)b * T_ + tk) * E_ + h * 64 + ch;
    const bf16_t* Kg = K + off;
    const bf16_t* Vg = V + off;
#pragma unroll
    for (int j = 0; j < 4; ++j)
      *(bf16x8*)&Ks[row][ch + j * 8] = *(const bf16x8*)(Kg + j * 8);
#pragma unroll
    for (int j = 0; j < 4; ++j) {
      bf16x8 va = *(const bf16x8*)(Vg + j * 8);
#pragma unroll
      for (int e = 0; e < 8; ++e) Vt[ch + j * 8 + e][row] = va[e];
    }
  }
  __syncthreads();

  const size_t rowbase = (size_t)(b * H_ + h) * (T_ >> s) + seg * 256;

#pragma unroll
  for (int sel = 0; sel < 2; ++sel) {
    const int tile = sel ? (15 - wv) : wv;   // causal load-balance pairing
    const int q = tile * 16 + lc;            // this lane's query row (swapped layout)

    const int tq = ((seg * 256 + q) << s) + g;
    const bf16_t* Qg = Q + ((size_t)b * T_ + tq) * E_ + h * 64 + lg * 8;
    bf16x8 qfrag0 = *(const bf16x8*)(Qg);
    bf16x8 qfrag1 = *(const bf16x8*)(Qg + 32);

    float m = -INFINITY, Z = 0.0f;
    f32x4 Oa[4] = {};

    const int nkb = tile / 4 + 1;   // 64-key blocks (causal)
    const int diag = tile / 4;
    for (int kb = 0; kb < nkb; ++kb) {
      // ---- S^T = K Q^T (64k x 16q): lane holds S[key=kt*16+lg*4+rg][q=lc] ----
      f32x4 sacc[4] = {};
      __builtin_amdgcn_s_setprio(1);
#pragma unroll
      for (int kt = 0; kt < 4; ++kt) {
        bf16x8 kf0 = *(const bf16x8*)&Ks[kb * 64 + kt * 16 + lc][lg * 8];
        bf16x8 kf1 = *(const bf16x8*)&Ks[kb * 64 + kt * 16 + lc][32 + lg * 8];
        sacc[kt] = __builtin_amdgcn_mfma_f32_16x16x32_bf16(kf0, qfrag0, sacc[kt], 0, 0, 0);
        sacc[kt] = __builtin_amdgcn_mfma_f32_16x16x32_bf16(kf1, qfrag1, sacc[kt], 0, 0, 0);
      }
      __builtin_amdgcn_s_setprio(0);
      if (kb == diag) {
#pragma unroll
        for (int kt = 0; kt < 4; ++kt)
#pragma unroll
          for (int rg = 0; rg < 4; ++rg)
            if (kb * 64 + kt * 16 + lg * 4 + rg > q) sacc[kt][rg] = -1e30f;
      }
      // ---- base-2 softmax, one pass over 16 in-lane scores, defer-max ----
      float pm = -1e30f;
#pragma unroll
      for (int kt = 0; kt < 4; ++kt) {
        pm = fmaxf(pm, fmaxf(fmaxf(sacc[kt][0], sacc[kt][1]),
                             fmaxf(sacc[kt][2], sacc[kt][3])));
      }
      pm = fmaxf(pm, __shfl_xor(pm, 16));
      pm = fmaxf(pm, __shfl_xor(pm, 32));
      if (!__all(pm - m <= 11.5f)) {
        const float nm = fmaxf(m, pm);
        const float crr = __builtin_amdgcn_exp2f(m - nm);
        Z *= crr;
#pragma unroll
        for (int dt = 0; dt < 4; ++dt)
#pragma unroll
          for (int rg = 0; rg < 4; ++rg) Oa[dt][rg] *= crr;
        m = nm;
      }
      float psum = 0.0f;
      bf16x4 pv[4];
#pragma unroll
      for (int kt = 0; kt < 4; ++kt)
#pragma unroll
        for (int rg = 0; rg < 4; ++rg) {
          const float p = __builtin_amdgcn_exp2f(sacc[kt][rg] - m);
          psum += p;
          pv[kt][rg] = (bf16_t)p;
        }
      psum += __shfl_xor(psum, 16);
      psum += __shfl_xor(psum, 32);
      Z += psum;
      // ---- PV in two 32-key half-passes through Pw ----
#pragma unroll
      for (int hf = 0; hf < 2; ++hf) {
        *(bf16x4*)&Pw[wv][lc][lg * 4]      = pv[hf * 2 + 0];
        *(bf16x4*)&Pw[wv][lc][16 + lg * 4] = pv[hf * 2 + 1];
        bf16x8 pb = *(const bf16x8*)&Pw[wv][lc][lg * 8];
        __builtin_amdgcn_s_setprio(1);
#pragma unroll
        for (int dt = 0; dt < 4; ++dt) {
          bf16x8 vf = *(const bf16x8*)&Vt[dt * 16 + lc][(kb * 2 + hf) * 32 + lg * 8];
          Oa[dt] = __builtin_amdgcn_mfma_f32_16x16x32_bf16(vf, pb, Oa[dt], 0, 0, 0);
        }
        __builtin_amdgcn_s_setprio(0);
      }
    }

    // ---- epilogue: lane holds O[q=lc][d=dt*16+lg*4+rg]; lse is base-2 ----
    const float lse = m + __builtin_amdgcn_logf(Z);
    const float iZ = 1.0f / Z;
    if (!S0) {
      bf16_t* orow = Ob + OB_OFF[s] + (rowbase + q) * 64 + lg * 4;
#pragma unroll
      for (int dt = 0; dt < 4; ++dt) {
        bf16x4 ov;
        ov[0] = (bf16_t)(Oa[dt][0] * iZ);
        ov[1] = (bf16_t)(Oa[dt][1] * iZ);
        ov[2] = (bf16_t)(Oa[dt][2] * iZ);
        ov[3] = (bf16_t)(Oa[dt][3] * iZ);
        *(bf16x4*)(orow + dt * 16) = ov;
      }
      if (lg == 0) Lse[LSE_OFF[s] + rowbase + q] = lse;
    } else {
      // in-register merge of late scales (stream-ordered: their dispatch is done)
      const int t_glob = seg * 256 + q;          // s=0 -> global position
      float o16[4][4];
#pragma unroll
      for (int dt = 0; dt < 4; ++dt)
#pragma unroll
        for (int rg = 0; rg < 4; ++rg) o16[dt][rg] = Oa[dt][rg] * iZ;
      float M = lse, S = 1.0f;
#pragma unroll
      for (int s2 = 1; s2 <= 4; ++s2) {
        const int r = 1 << s2;
        const int gg = h >> (4 - s2);
        if ((t_glob & (r - 1)) != gg) continue;
        const size_t idx = (size_t)(b * H_ + h) * (T_ >> s2) + (t_glob >> s2);
        const float l2 = Lse[LSE_OFF[s2] + idx];
        const bf16_t* orow = Ob + OB_OFF[s2] + idx * 64 + lg * 4;
        const float nM = fmaxf(M, l2);
        const float a = __builtin_amdgcn_exp2f(M - nM);
        const float e = __builtin_amdgcn_exp2f(l2 - nM);
#pragma unroll
        for (int dt = 0; dt < 4; ++dt) {
          const bf16x4 ov = *(const bf16x4*)(orow + dt * 16);
#pragma unroll
          for (int rg = 0; rg < 4; ++rg)
            o16[dt][rg] = o16[dt][rg] * a + (float)ov[rg] * e;
        }
        S = S * a + e;
        M = nM;
      }
      const float invS = 1.0f / S;
      bf16_t* yrow = Y + ((size_t)b * T_ + t_glob) * E_ + h * 64 + lg * 4;
#pragma unroll
      for (int dt = 0; dt < 4; ++dt) {
        bf16x4 ov;
        ov[0] = (bf16_t)(o16[dt][0] * invS);
        ov[1] = (bf16_t)(o16[dt][1] * invS);
        ov[2] = (bf16_t)(o16[dt][2] * invS);
        ov[3] = (bf16_t)(o16[dt][3] * invS);
        *(bf16x4*)(yrow + dt * 16) = ov;
      }
    }
  }
}

extern "C" void kernel_launch(void* const* d_in, const int* in_sizes, int n_in,
                              void* d_out, int out_size, void* d_ws, size_t ws_size,
                              hipStream_t stream) {
  (void)in_sizes; (void)n_in; (void)out_size; (void)ws_size;
  const float* x  = (const float*)d_in[0];
  const float* wq = (const float*)d_in[1];
  const float* bq = (const float*)d_in[2];
  const float* wk = (const float*)d_in[3];
  const float* bk = (const float*)d_in[4];
  const float* wv = (const float*)d_in[5];
  const float* bv = (const float*)d_in[6];
  const float* wo = (const float*)d_in[7];
  const float* bo = (const float*)d_in[8];

  char* p = (char*)d_ws;
  auto take = [&](size_t bytes) {
    char* q = p;
    p += (bytes + 255) & ~(size_t)255;
    return (void*)q;
  };
  bf16_t* wq_t = (bf16_t*)take((size_t)E_ * E_ * 2);  // wq_t/wk_t/wv_t contiguous
  bf16_t* wk_t = (bf16_t*)take((size_t)E_ * E_ * 2);
  bf16_t* wv_t = (bf16_t*)take((size_t)E_ * E_ * 2);
  bf16_t* wo_t = (bf16_t*)take((size_t)E_ * E_ * 2);
  bf16_t* xb   = (bf16_t*)take((size_t)M_ * E_ * 2);
  bf16_t* qb   = (bf16_t*)take((size_t)M_ * E_ * 2);  // qb/kbuf/vbuf contiguous
  bf16_t* kbuf = (bf16_t*)take((size_t)M_ * E_ * 2);
  bf16_t* vbuf = (bf16_t*)take((size_t)M_ * E_ * 2);
  bf16_t* yb   = (bf16_t*)take((size_t)M_ * E_ * 2);
  bf16_t* Ob   = (bf16_t*)take(OB_TOTAL * 2);
  float*  Lse  = (float*)take(LSE_TOTAL * 4);
  (void)wk_t; (void)wv_t;

  cvt_f32_bf16<<<M_ * E_ / 1024, 256, 0, stream>>>(x, xb);
  cvt_transpose_w<<<dim3(32, 32, 4), 256, 0, stream>>>(wq, wk, wv, wo, wq_t, wk_t, wv_t, wo_t);

  // Fused Q/K/V projection: 128x128 tiles, multi-block/CU, swizzled. Q scale
  // folds log2(e) so attention softmax runs in base 2.
  gemm_bt<true, true><<<dim3(M_ / 128, 24), 256, 0, stream>>>(
      xb, wq_t, bq, bk, bv, qb, 0.125f * 1.44269504f);

  // Scales 1-4 (480 blocks) -> compact Ob/Lse.
  attn_inst<false><<<480, 512, 0, stream>>>(qb, kbuf, vbuf, Ob, Lse, yb);
  // Scale 0 (512 blocks) + in-register merge + y write. No merge dispatch.
  attn_inst<true><<<512, 512, 0, stream>>>(qb, kbuf, vbuf, Ob, Lse, yb);

  // Output projection.
  gemm_bt<false, false><<<dim3(M_ / 128, 8), 256, 0, stream>>>(
      yb, wo_t, bo, bo, bo, d_out, 1.0f);
}